// Round 4
// baseline (701.935 us; speedup 1.0000x reference)
//
#include <hip/hip_runtime.h>

typedef __attribute__((ext_vector_type(8))) short bfrag;   // 8 x bf16 (4 VGPRs)
typedef __attribute__((ext_vector_type(4))) float ffrag;   // 4 x f32 accum

struct alignas(16) U8v { unsigned int u[4]; };

__device__ __forceinline__ unsigned int cvt_pk_bf16(float lo, float hi) {
    unsigned int r;
    asm("v_cvt_pk_bf16_f32 %0, %1, %2" : "=v"(r) : "v"(lo), "v"(hi));
    return r;
}
__device__ __forceinline__ unsigned short f2bf1(float x) {
    return (unsigned short)cvt_pk_bf16(x, x);
}

// ---- prep: transpose + bf16-convert weights into workspace ----
__global__ void prep_kernel(const float* __restrict__ Wlin,
                            const float* __restrict__ W1,
                            const float* __restrict__ W2,
                            unsigned short* __restrict__ wlinT,
                            unsigned short* __restrict__ w1T,
                            unsigned short* __restrict__ w2T) {
    int idx = blockIdx.x * 256 + threadIdx.x;           // 0..32767
    {   // W_lin [256][128] -> wlinT [128][256]
        int e = idx >> 7, h = idx & 127;
        wlinT[h * 256 + e] = f2bf1(Wlin[idx]);
    }
    if (idx < 128 * 128) {  // W1/W2 [128][128] -> transposed
        int h = idx >> 7, f = idx & 127;
        w1T[f * 128 + h] = f2bf1(W1[idx]);
        w2T[f * 128 + h] = f2bf1(W2[idx]);
    }
}

// ---- fused per-node kernel: 1 block = 1 node (32 edges) ----
// LDS 18.4KB, VGPR<=64 -> 8 blocks/CU (32 waves) for latency hiding.
__global__ __launch_bounds__(256, 8) void fused_kernel(
    const float* __restrict__ ef, const int* __restrict__ mask,
    const unsigned short* __restrict__ wlinT,
    const unsigned short* __restrict__ w1T,
    const unsigned short* __restrict__ w2T,
    const float* __restrict__ b_lin, const float* __restrict__ g_edge,
    const float* __restrict__ b_edge, const float* __restrict__ b1,
    const float* __restrict__ b2, const float* __restrict__ g_node,
    const float* __restrict__ b_node,
    float* __restrict__ out_node, float* __restrict__ out_edge) {

    __shared__ char  smem[16384];   // phase1-2: ef bf16 [32 rows x 512B, swz]
                                    // phase4+: [0:8K)=h_norm bf16 [32x256B, swz], [8K:16K)=gelu
    __shared__ float s_part[256];   // per-wave LN partials: w*64 + row*2 + {sum,sq}
    __shared__ float s_red[256];    // [0:32)mu [32:64)rstd [64:96)maskf [96:224)node vals [224]mu [225]rstd

    const int tid = threadIdx.x;
    const int w = tid >> 6, lane = tid & 63, q = lane >> 4, c = lane & 15;
    const int n = blockIdx.x;
    const float* efn = ef + (size_t)n * 8192;

    if (tid < 32) s_red[64 + tid] = (mask[n * 32 + tid] != 0) ? 1.f : 0.f;

    // ---- phase 1: stage edge_features -> bf16 LDS (swizzled 16B slots) ----
    #pragma unroll
    for (int i = 0; i < 4; ++i) {
        int s = i * 256 + tid;          // 16B-slot id, 1024 slots (32 rows x 32 slots)
        int row = s >> 5, cs = s & 31;
        const float4* p = (const float4*)(efn + (size_t)s * 8);
        float4 v0 = p[0], v1 = p[1];
        U8v u;
        u.u[0] = cvt_pk_bf16(v0.x, v0.y); u.u[1] = cvt_pk_bf16(v0.z, v0.w);
        u.u[2] = cvt_pk_bf16(v1.x, v1.y); u.u[3] = cvt_pk_bf16(v1.z, v1.w);
        *(U8v*)(smem + row * 512 + ((cs * 16) ^ ((row & 7) << 4))) = u;
    }
    __syncthreads();

    // ---- phase 2: edge_hidden = ef @ W_lin  (M=32,K=256,N=128), kept in regs ----
    ffrag acc[2][2] = {};
    #pragma unroll
    for (int kk = 0; kk < 8; ++kk) {
        bfrag a[2], b[2];
        #pragma unroll
        for (int m = 0; m < 2; ++m) {
            int row = 16 * m + c;
            a[m] = *(const bfrag*)(smem + row * 512 + ((kk * 64 + q * 16) ^ ((row & 7) << 4)));
        }
        #pragma unroll
        for (int j = 0; j < 2; ++j) {
            int col = 32 * w + 16 * j + c;
            b[j] = *(const bfrag*)(wlinT + col * 256 + kk * 32 + q * 8);
        }
        #pragma unroll
        for (int m = 0; m < 2; ++m)
            #pragma unroll
            for (int j = 0; j < 2; ++j)
                acc[m][j] = __builtin_amdgcn_mfma_f32_16x16x32_bf16(a[m], b[j], acc[m][j], 0, 0, 0);
    }
    float h[2][2][4];
    #pragma unroll
    for (int j = 0; j < 2; ++j) {
        float bl = b_lin[32 * w + 16 * j + c];
        #pragma unroll
        for (int m = 0; m < 2; ++m)
            #pragma unroll
            for (int r = 0; r < 4; ++r)
                h[m][j][r] = acc[m][j][r] + bl;
    }

    // ---- edge-LN stats: in-wave reduce over c (16 lanes), cross-wave via LDS ----
    #pragma unroll
    for (int m = 0; m < 2; ++m)
        #pragma unroll
        for (int r = 0; r < 4; ++r) {
            float s  = h[m][0][r] + h[m][1][r];
            float qv = h[m][0][r] * h[m][0][r] + h[m][1][r] * h[m][1][r];
            #pragma unroll
            for (int d = 1; d < 16; d <<= 1) { s += __shfl_xor(s, d); qv += __shfl_xor(qv, d); }
            if (c == 0) {
                int row = 16 * m + 4 * q + r;
                s_part[w * 64 + row * 2]     = s;
                s_part[w * 64 + row * 2 + 1] = qv;
            }
        }
    __syncthreads();
    if (tid < 32) {
        float s = 0.f, qv = 0.f;
        #pragma unroll
        for (int ww = 0; ww < 4; ++ww) { s += s_part[ww * 64 + tid * 2]; qv += s_part[ww * 64 + tid * 2 + 1]; }
        float mu = s * (1.f / 128.f);
        float var = qv * (1.f / 128.f) - mu * mu;
        s_red[tid] = mu;
        s_red[32 + tid] = rsqrtf(var + 1e-5f);
    }
    __syncthreads();

    // ---- phase 4: normalize from regs -> bf16 h_norm in LDS (scattered b16, swz) ----
    float gc[2], bc[2];
    #pragma unroll
    for (int j = 0; j < 2; ++j) {
        int col = 32 * w + 16 * j + c;
        gc[j] = g_edge[col]; bc[j] = b_edge[col];
    }
    #pragma unroll
    for (int m = 0; m < 2; ++m)
        #pragma unroll
        for (int r = 0; r < 4; ++r) {
            int row = 16 * m + 4 * q + r;
            float mu = s_red[row], rs = s_red[32 + row];
            #pragma unroll
            for (int j = 0; j < 2; ++j) {
                int col = 32 * w + 16 * j + c;
                float x = (h[m][j][r] - mu) * rs * gc[j] + bc[j];
                *(unsigned short*)(smem + row * 256 + ((col * 2) ^ ((row & 7) << 4))) = f2bf1(x);
            }
        }
    __syncthreads();

    // ---- phase 5: FFN1 + gelu (M=32,K=128,N=128) ----
    ffrag acc2[2][2] = {};
    #pragma unroll
    for (int kk = 0; kk < 4; ++kk) {
        bfrag a[2], b[2];
        #pragma unroll
        for (int m = 0; m < 2; ++m) {
            int row = 16 * m + c;
            a[m] = *(const bfrag*)(smem + row * 256 + ((kk * 64 + q * 16) ^ ((row & 7) << 4)));
        }
        #pragma unroll
        for (int j = 0; j < 2; ++j) {
            int col = 32 * w + 16 * j + c;
            b[j] = *(const bfrag*)(w1T + col * 128 + kk * 32 + q * 8);
        }
        #pragma unroll
        for (int m = 0; m < 2; ++m)
            #pragma unroll
            for (int j = 0; j < 2; ++j)
                acc2[m][j] = __builtin_amdgcn_mfma_f32_16x16x32_bf16(a[m], b[j], acc2[m][j], 0, 0, 0);
    }
    {
        float b1c[2];
        #pragma unroll
        for (int j = 0; j < 2; ++j) b1c[j] = b1[32 * w + 16 * j + c];
        #pragma unroll
        for (int m = 0; m < 2; ++m)
            #pragma unroll
            for (int j = 0; j < 2; ++j) {
                int col = 32 * w + 16 * j + c;
                #pragma unroll
                for (int r = 0; r < 4; ++r) {
                    int row = 16 * m + 4 * q + r;
                    float x = acc2[m][j][r] + b1c[j];
                    // gelu(tanh approx) = x * sigmoid(2*0.79788456*(x+0.044715x^3))
                    float y = 0.7978845608028654f * x * (1.f + 0.044715f * x * x);
                    float e;
                    asm("v_exp_f32 %0, %1" : "=v"(e) : "v"(-2.885390081777927f * y)); // 2^(-2y*log2e)
                    float rcp;
                    asm("v_rcp_f32 %0, %1" : "=v"(rcp) : "v"(1.f + e));
                    float ge = x * rcp;
                    *(unsigned short*)(smem + 8192 + row * 256 + ((col * 2) ^ ((row & 7) << 4))) = f2bf1(ge);
                }
            }
    }
    __syncthreads();

    // ---- phase 6: FFN2 + residual -> edge_output; masked row-agg in regs ----
    ffrag acc3[2][2] = {};
    #pragma unroll
    for (int kk = 0; kk < 4; ++kk) {
        bfrag a[2], b[2];
        #pragma unroll
        for (int m = 0; m < 2; ++m) {
            int row = 16 * m + c;
            a[m] = *(const bfrag*)(smem + 8192 + row * 256 + ((kk * 64 + q * 16) ^ ((row & 7) << 4)));
        }
        #pragma unroll
        for (int j = 0; j < 2; ++j) {
            int col = 32 * w + 16 * j + c;
            b[j] = *(const bfrag*)(w2T + col * 128 + kk * 32 + q * 8);
        }
        #pragma unroll
        for (int m = 0; m < 2; ++m)
            #pragma unroll
            for (int j = 0; j < 2; ++j)
                acc3[m][j] = __builtin_amdgcn_mfma_f32_16x16x32_bf16(a[m], b[j], acc3[m][j], 0, 0, 0);
    }
    float* eo_n = out_edge + (size_t)n * 4096;
    float np0 = 0.f, np1 = 0.f;
    {
        float b2c[2];
        #pragma unroll
        for (int j = 0; j < 2; ++j) b2c[j] = b2[32 * w + 16 * j + c];
        #pragma unroll
        for (int m = 0; m < 2; ++m)
            #pragma unroll
            for (int r = 0; r < 4; ++r) {
                int row = 16 * m + 4 * q + r;
                float mv = s_red[64 + row];
                {
                    int col = 32 * w + c;
                    float v = acc3[m][0][r] + b2c[0] + h[m][0][r];
                    eo_n[row * 128 + col] = v;
                    np0 += mv * v;
                }
                {
                    int col = 32 * w + 16 + c;
                    float v = acc3[m][1][r] + b2c[1] + h[m][1][r];
                    eo_n[row * 128 + col] = v;
                    np1 += mv * v;
                }
            }
    }
    np0 += __shfl_xor(np0, 16); np0 += __shfl_xor(np0, 32);
    np1 += __shfl_xor(np1, 16); np1 += __shfl_xor(np1, 32);
    if (q == 0) {
        s_red[96 + 32 * w + c]      = np0;
        s_red[96 + 32 * w + 16 + c] = np1;
    }
    __syncthreads();

    // ---- phase 7: node LN ----
    if (tid < 64) {
        float v0 = s_red[96 + tid], v1 = s_red[160 + tid];
        float s = v0 + v1, qv = v0 * v0 + v1 * v1;
        #pragma unroll
        for (int d = 1; d < 64; d <<= 1) { s += __shfl_xor(s, d); qv += __shfl_xor(qv, d); }
        if (tid == 0) {
            float mu = s * (1.f / 128.f);
            float var = qv * (1.f / 128.f) - mu * mu;
            s_red[224] = mu;
            s_red[225] = rsqrtf(var + 1e-5f);
        }
    }
    __syncthreads();
    if (tid < 128) {
        float nv = s_red[96 + tid];
        out_node[(size_t)n * 128 + tid] = (nv - s_red[224]) * s_red[225] * g_node[tid] + b_node[tid];
    }
}

extern "C" void kernel_launch(void* const* d_in, const int* in_sizes, int n_in,
                              void* d_out, int out_size, void* d_ws, size_t ws_size,
                              hipStream_t stream) {
    const float* ef     = (const float*)d_in[0];
    const int*   mask   = (const int*)d_in[1];
    const float* Wlin   = (const float*)d_in[2];
    const float* b_lin  = (const float*)d_in[3];
    const float* g_edge = (const float*)d_in[4];
    const float* b_edge = (const float*)d_in[5];
    const float* W1     = (const float*)d_in[6];
    const float* b1     = (const float*)d_in[7];
    const float* W2     = (const float*)d_in[8];
    const float* b2     = (const float*)d_in[9];
    const float* g_node = (const float*)d_in[10];
    const float* b_node = (const float*)d_in[11];

    int N = in_sizes[0] / (32 * 256);

    unsigned short* wlinT = (unsigned short*)d_ws;       // [128][256]
    unsigned short* w1T   = wlinT + 128 * 256;           // [128][128]
    unsigned short* w2T   = w1T + 128 * 128;             // [128][128]

    float* out_node = (float*)d_out;
    float* out_edge = out_node + (size_t)N * 128;

    prep_kernel<<<128, 256, 0, stream>>>(Wlin, W1, W2, wlinT, w1T, w2T);
    fused_kernel<<<N, 256, 0, stream>>>(ef, mask, wlinT, w1T, w2T,
                                        b_lin, g_edge, b_edge, b1, b2,
                                        g_node, b_node, out_node, out_edge);
}

// Round 5
// 680.806 us; speedup vs baseline: 1.0310x; 1.0310x over previous
//
#include <hip/hip_runtime.h>

typedef __attribute__((ext_vector_type(8))) short bfrag;   // 8 x bf16 (4 VGPRs)
typedef __attribute__((ext_vector_type(4))) float ffrag;   // 4 x f32 accum

struct alignas(16) U8v { unsigned int u[4]; };

__device__ __forceinline__ unsigned int cvt_pk_bf16(float lo, float hi) {
    unsigned int r;
    asm("v_cvt_pk_bf16_f32 %0, %1, %2" : "=v"(r) : "v"(lo), "v"(hi));
    return r;
}
__device__ __forceinline__ unsigned short f2bf1(float x) {
    return (unsigned short)cvt_pk_bf16(x, x);
}

#define GRID 2048

// ---- prep: transpose + bf16-convert weights into workspace ----
__global__ void prep_kernel(const float* __restrict__ Wlin,
                            const float* __restrict__ W1,
                            const float* __restrict__ W2,
                            unsigned short* __restrict__ wlinT,
                            unsigned short* __restrict__ w1T,
                            unsigned short* __restrict__ w2T) {
    int idx = blockIdx.x * 256 + threadIdx.x;           // 0..32767
    {   // W_lin [256][128] -> wlinT [128][256]
        int e = idx >> 7, h = idx & 127;
        wlinT[h * 256 + e] = f2bf1(Wlin[idx]);
    }
    if (idx < 128 * 128) {  // W1/W2 [128][128] -> transposed
        int h = idx >> 7, f = idx & 127;
        w1T[f * 128 + h] = f2bf1(W1[idx]);
        w2T[f * 128 + h] = f2bf1(W2[idx]);
    }
}

// ---- persistent fused kernel: 512 threads (8 waves), each wave owns 16 cols.
// W1/W2 fragments resident in VGPRs across the node loop; Wlin streamed from L2.
// Next node's edge_features prefetched into regs during compute (T14 split).
__global__ __launch_bounds__(512, 4) void fused_kernel(
    const float* __restrict__ ef, const int* __restrict__ mask,
    const unsigned short* __restrict__ wlinT,
    const unsigned short* __restrict__ w1T,
    const unsigned short* __restrict__ w2T,
    const float* __restrict__ b_lin, const float* __restrict__ g_edge,
    const float* __restrict__ b_edge, const float* __restrict__ b1,
    const float* __restrict__ b2, const float* __restrict__ g_node,
    const float* __restrict__ b_node,
    float* __restrict__ out_node, float* __restrict__ out_edge, int N) {

    __shared__ char  s_ef[16384];   // ef bf16 [32 rows x 512B, swizzled]
    __shared__ char  s_hn[8192];    // h_norm bf16 [32 x 256B, swizzled]
    __shared__ char  s_g[8192];     // gelu bf16 [32 x 256B, swizzled]
    __shared__ float s_part[512];   // LN partials: w*64 + row*2 + {sum,sq}
    __shared__ float s_red[256];    // [0:32)mu [32:64)rstd [64:96)maskf [96:224)nodevals [224]mu [225]rstd

    const int tid = threadIdx.x;
    const int w = tid >> 6, lane = tid & 63, q = lane >> 4, c = lane & 15;
    const int col = 16 * w + c;

    if (blockIdx.x >= N) return;

    // per-lane resident scalars
    const float blc = b_lin[col], gc = g_edge[col], bc = b_edge[col];
    const float b1c = b1[col],    b2c = b2[col];
    float gn = 0.f, bn = 0.f;
    if (tid < 128) { gn = g_node[tid]; bn = b_node[tid]; }

    // resident W1/W2 fragments (16 cols per wave -> 16+16 VGPRs)
    bfrag W1r[4], W2r[4];
    #pragma unroll
    for (int kk = 0; kk < 4; ++kk) {
        W1r[kk] = *(const bfrag*)(w1T + col * 128 + kk * 32 + q * 8);
        W2r[kk] = *(const bfrag*)(w2T + col * 128 + kk * 32 + q * 8);
    }

    int n = blockIdx.x;
    {   // initial stage of node n: 2 slots of 8 f32 per thread
        const float* efn = ef + (size_t)n * 8192;
        #pragma unroll
        for (int i = 0; i < 2; ++i) {
            int s = i * 512 + tid;
            int row = s >> 5, cs = s & 31;
            const float4* p = (const float4*)(efn + (size_t)s * 8);
            float4 v0 = p[0], v1 = p[1];
            U8v u;
            u.u[0] = cvt_pk_bf16(v0.x, v0.y); u.u[1] = cvt_pk_bf16(v0.z, v0.w);
            u.u[2] = cvt_pk_bf16(v1.x, v1.y); u.u[3] = cvt_pk_bf16(v1.z, v1.w);
            *(U8v*)(s_ef + row * 512 + ((cs * 16) ^ ((row & 7) << 4))) = u;
        }
        if (tid < 32) s_red[64 + tid] = (mask[(size_t)n * 32 + tid] != 0) ? 1.f : 0.f;
    }
    __syncthreads();

    for (;;) {
        const int n_next = n + GRID;
        const bool has_next = n_next < N;

        // ---- MFMA1: h = ef @ Wlin + b_lin (Wlin streamed from L2) ----
        ffrag acc[2] = {};
        #pragma unroll
        for (int kk = 0; kk < 8; ++kk) {
            bfrag a0, a1, b;
            { int row = c;      a0 = *(const bfrag*)(s_ef + row * 512 + ((kk * 64 + q * 16) ^ ((row & 7) << 4))); }
            { int row = 16 + c; a1 = *(const bfrag*)(s_ef + row * 512 + ((kk * 64 + q * 16) ^ ((row & 7) << 4))); }
            b = *(const bfrag*)(wlinT + col * 256 + kk * 32 + q * 8);
            acc[0] = __builtin_amdgcn_mfma_f32_16x16x32_bf16(a0, b, acc[0], 0, 0, 0);
            acc[1] = __builtin_amdgcn_mfma_f32_16x16x32_bf16(a1, b, acc[1], 0, 0, 0);
        }
        float h[2][4];
        #pragma unroll
        for (int m = 0; m < 2; ++m)
            #pragma unroll
            for (int r = 0; r < 4; ++r)
                h[m][r] = acc[m][r] + blc;

        // ---- issue next-node prefetch loads (consumed at end of iter) ----
        float4 pf0, pf1, pf2, pf3;
        if (has_next) {
            const float* efn2 = ef + (size_t)n_next * 8192;
            const float4* pa = (const float4*)(efn2 + (size_t)tid * 8);
            const float4* pb = (const float4*)(efn2 + (size_t)(512 + tid) * 8);
            pf0 = pa[0]; pf1 = pa[1]; pf2 = pb[0]; pf3 = pb[1];
        }

        // ---- edge-LN stats: reduce over c lanes, then cross-wave ----
        #pragma unroll
        for (int m = 0; m < 2; ++m)
            #pragma unroll
            for (int r = 0; r < 4; ++r) {
                float s = h[m][r], qv = h[m][r] * h[m][r];
                #pragma unroll
                for (int d = 1; d < 16; d <<= 1) { s += __shfl_xor(s, d); qv += __shfl_xor(qv, d); }
                if (c == 0) {
                    int row = 16 * m + 4 * q + r;
                    s_part[w * 64 + row * 2]     = s;
                    s_part[w * 64 + row * 2 + 1] = qv;
                }
            }
        __syncthreads();
        if (tid < 32) {
            float s = 0.f, qv = 0.f;
            #pragma unroll
            for (int ww = 0; ww < 8; ++ww) { s += s_part[ww * 64 + tid * 2]; qv += s_part[ww * 64 + tid * 2 + 1]; }
            float mu = s * (1.f / 128.f);
            float var = qv * (1.f / 128.f) - mu * mu;
            s_red[tid] = mu;
            s_red[32 + tid] = rsqrtf(var + 1e-5f);
        }
        __syncthreads();

        // ---- h_norm -> bf16 LDS ----
        #pragma unroll
        for (int m = 0; m < 2; ++m)
            #pragma unroll
            for (int r = 0; r < 4; ++r) {
                int row = 16 * m + 4 * q + r;
                float x = (h[m][r] - s_red[row]) * s_red[32 + row] * gc + bc;
                *(unsigned short*)(s_hn + row * 256 + ((col * 2) ^ ((row & 7) << 4))) = f2bf1(x);
            }
        __syncthreads();

        // ---- FFN1 + gelu (W1 resident) ----
        ffrag acc2[2] = {};
        #pragma unroll
        for (int kk = 0; kk < 4; ++kk) {
            bfrag a0, a1;
            { int row = c;      a0 = *(const bfrag*)(s_hn + row * 256 + ((kk * 64 + q * 16) ^ ((row & 7) << 4))); }
            { int row = 16 + c; a1 = *(const bfrag*)(s_hn + row * 256 + ((kk * 64 + q * 16) ^ ((row & 7) << 4))); }
            acc2[0] = __builtin_amdgcn_mfma_f32_16x16x32_bf16(a0, W1r[kk], acc2[0], 0, 0, 0);
            acc2[1] = __builtin_amdgcn_mfma_f32_16x16x32_bf16(a1, W1r[kk], acc2[1], 0, 0, 0);
        }
        #pragma unroll
        for (int m = 0; m < 2; ++m)
            #pragma unroll
            for (int r = 0; r < 4; ++r) {
                int row = 16 * m + 4 * q + r;
                float x = acc2[m][r] + b1c;
                float y = 0.7978845608028654f * x * (1.f + 0.044715f * x * x);
                float e;
                asm("v_exp_f32 %0, %1" : "=v"(e) : "v"(-2.885390081777927f * y));
                float rcp;
                asm("v_rcp_f32 %0, %1" : "=v"(rcp) : "v"(1.f + e));
                float ge = x * rcp;
                *(unsigned short*)(s_g + row * 256 + ((col * 2) ^ ((row & 7) << 4))) = f2bf1(ge);
            }
        __syncthreads();

        // ---- FFN2 + residual -> edge_output; masked aggregation ----
        ffrag acc3[2] = {};
        #pragma unroll
        for (int kk = 0; kk < 4; ++kk) {
            bfrag a0, a1;
            { int row = c;      a0 = *(const bfrag*)(s_g + row * 256 + ((kk * 64 + q * 16) ^ ((row & 7) << 4))); }
            { int row = 16 + c; a1 = *(const bfrag*)(s_g + row * 256 + ((kk * 64 + q * 16) ^ ((row & 7) << 4))); }
            acc3[0] = __builtin_amdgcn_mfma_f32_16x16x32_bf16(a0, W2r[kk], acc3[0], 0, 0, 0);
            acc3[1] = __builtin_amdgcn_mfma_f32_16x16x32_bf16(a1, W2r[kk], acc3[1], 0, 0, 0);
        }
        float* eo_n = out_edge + (size_t)n * 4096;
        float nv = 0.f;
        #pragma unroll
        for (int m = 0; m < 2; ++m)
            #pragma unroll
            for (int r = 0; r < 4; ++r) {
                int row = 16 * m + 4 * q + r;
                float v = acc3[m][r] + b2c + h[m][r];
                eo_n[row * 128 + col] = v;
                nv += s_red[64 + row] * v;
            }
        nv += __shfl_xor(nv, 16);
        nv += __shfl_xor(nv, 32);
        if (q == 0) s_red[96 + col] = nv;

        // ---- write prefetched ef into s_ef (safe: last s_ef read was MFMA1) ----
        if (has_next) {
            {
                int s = tid, row = s >> 5, cs = s & 31;
                U8v u;
                u.u[0] = cvt_pk_bf16(pf0.x, pf0.y); u.u[1] = cvt_pk_bf16(pf0.z, pf0.w);
                u.u[2] = cvt_pk_bf16(pf1.x, pf1.y); u.u[3] = cvt_pk_bf16(pf1.z, pf1.w);
                *(U8v*)(s_ef + row * 512 + ((cs * 16) ^ ((row & 7) << 4))) = u;
            }
            {
                int s = 512 + tid, row = s >> 5, cs = s & 31;
                U8v u;
                u.u[0] = cvt_pk_bf16(pf2.x, pf2.y); u.u[1] = cvt_pk_bf16(pf2.z, pf2.w);
                u.u[2] = cvt_pk_bf16(pf3.x, pf3.y); u.u[3] = cvt_pk_bf16(pf3.z, pf3.w);
                *(U8v*)(s_ef + row * 512 + ((cs * 16) ^ ((row & 7) << 4))) = u;
            }
        }
        __syncthreads();   // A: nodevals + s_ef complete

        if (tid < 64) {    // node-LN stats (wave 0)
            float v0 = s_red[96 + tid], v1 = s_red[160 + tid];
            float s = v0 + v1, qv = v0 * v0 + v1 * v1;
            #pragma unroll
            for (int d = 1; d < 64; d <<= 1) { s += __shfl_xor(s, d); qv += __shfl_xor(qv, d); }
            if (tid == 0) {
                float mu = s * (1.f / 128.f);
                float var = qv * (1.f / 128.f) - mu * mu;
                s_red[224] = mu;
                s_red[225] = rsqrtf(var + 1e-5f);
            }
        } else if (has_next && tid < 96) {   // next node's mask (wave 1)
            s_red[tid] = (mask[(size_t)n_next * 32 + (tid - 64)] != 0) ? 1.f : 0.f;
        }
        __syncthreads();   // B

        if (tid < 128) {
            float x = s_red[96 + tid];
            out_node[(size_t)n * 128 + tid] = (x - s_red[224]) * s_red[225] * gn + bn;
        }

        if (!has_next) break;
        n = n_next;
    }
}

extern "C" void kernel_launch(void* const* d_in, const int* in_sizes, int n_in,
                              void* d_out, int out_size, void* d_ws, size_t ws_size,
                              hipStream_t stream) {
    const float* ef     = (const float*)d_in[0];
    const int*   mask   = (const int*)d_in[1];
    const float* Wlin   = (const float*)d_in[2];
    const float* b_lin  = (const float*)d_in[3];
    const float* g_edge = (const float*)d_in[4];
    const float* b_edge = (const float*)d_in[5];
    const float* W1     = (const float*)d_in[6];
    const float* b1     = (const float*)d_in[7];
    const float* W2     = (const float*)d_in[8];
    const float* b2     = (const float*)d_in[9];
    const float* g_node = (const float*)d_in[10];
    const float* b_node = (const float*)d_in[11];

    int N = in_sizes[0] / (32 * 256);

    unsigned short* wlinT = (unsigned short*)d_ws;       // [128][256]
    unsigned short* w1T   = wlinT + 128 * 256;           // [128][128]
    unsigned short* w2T   = w1T + 128 * 128;             // [128][128]

    float* out_node = (float*)d_out;
    float* out_edge = out_node + (size_t)N * 128;

    prep_kernel<<<128, 256, 0, stream>>>(Wlin, W1, W2, wlinT, w1T, w2T);
    int grid = N < GRID ? N : GRID;
    fused_kernel<<<grid, 512, 0, stream>>>(ef, mask, wlinT, w1T, w2T,
                                           b_lin, g_edge, b_edge, b1, b2,
                                           g_node, b_node, out_node, out_edge, N);
}

// Round 6
// 396.228 us; speedup vs baseline: 1.7715x; 1.7182x over previous
//
#include <hip/hip_runtime.h>

typedef __attribute__((ext_vector_type(8))) short bfrag;   // 8 x bf16 (4 VGPRs)
typedef __attribute__((ext_vector_type(4))) float ffrag;   // 4 x f32 accum

struct alignas(16) U8v { unsigned int u[4]; };

__device__ __forceinline__ unsigned int cvt_pk_bf16(float lo, float hi) {
    unsigned int r;
    asm("v_cvt_pk_bf16_f32 %0, %1, %2" : "=v"(r) : "v"(lo), "v"(hi));
    return r;
}
__device__ __forceinline__ unsigned short f2bf1(float x) {
    return (unsigned short)cvt_pk_bf16(x, x);
}

// ---- prep: transpose + bf16-convert weights into workspace ----
__global__ void prep_kernel(const float* __restrict__ Wlin,
                            const float* __restrict__ W1,
                            const float* __restrict__ W2,
                            unsigned short* __restrict__ wlinT,
                            unsigned short* __restrict__ w1T,
                            unsigned short* __restrict__ w2T) {
    int idx = blockIdx.x * 256 + threadIdx.x;           // 0..32767
    {   // W_lin [256][128] -> wlinT [128][256]
        int e = idx >> 7, h = idx & 127;
        wlinT[h * 256 + e] = f2bf1(Wlin[idx]);
    }
    if (idx < 128 * 128) {  // W1/W2 [128][128] -> transposed
        int h = idx >> 7, f = idx & 127;
        w1T[f * 128 + h] = f2bf1(W1[idx]);
        w2T[f * 128 + h] = f2bf1(W2[idx]);
    }
}

// ---- fused kernel: 1 block = 2 nodes = 64 edge rows, 256 threads (4 waves).
// Wave w owns output cols [32w, 32w+32). No forced occupancy (spill evidence
// r4/r5): (256,4) = 128-reg budget, measured footprint ~110.
__global__ __launch_bounds__(256, 4) void fused_kernel(
    const float* __restrict__ ef, const int* __restrict__ mask,
    const unsigned short* __restrict__ wlinT,
    const unsigned short* __restrict__ w1T,
    const unsigned short* __restrict__ w2T,
    const float* __restrict__ b_lin, const float* __restrict__ g_edge,
    const float* __restrict__ b_edge, const float* __restrict__ b1,
    const float* __restrict__ b2, const float* __restrict__ g_node,
    const float* __restrict__ b_node,
    float* __restrict__ out_node, float* __restrict__ out_edge, int N) {

    __shared__ char  smem[32768];   // phase1-2: ef bf16 [64 rows x 512B, swz]
                                    // later: [0:16K) h_norm bf16 [64x256B, swz], [16K:32K) gelu
    __shared__ float s_part[512];   // LN partials: w*128 + row*2 + {sum,sq}
    __shared__ float s_stat[128];   // [0:64) mu, [64:128) rstd
    __shared__ float s_mask[64];
    __shared__ float s_nv[256];     // [node][128] aggregated node vals

    const int tid = threadIdx.x;
    const int w = tid >> 6, lane = tid & 63, q = lane >> 4, c = lane & 15;
    const int col0 = 32 * w + c, col1 = 32 * w + 16 + c;

    // odd-N tail: overlap previous block's rows (stores idempotent)
    int row_base = blockIdx.x * 64;
    if (row_base + 64 > N * 32) row_base = N * 32 - 64;
    const int n0 = row_base >> 5;                        // first of 2 nodes
    const float* efb = ef + (size_t)row_base * 256;

    if (tid < 64) s_mask[tid] = (mask[(size_t)row_base + tid] != 0) ? 1.f : 0.f;

    // ---- phase 1: stage 64 rows of edge_features -> bf16 LDS (swizzled) ----
    #pragma unroll
    for (int i = 0; i < 8; ++i) {
        int s = i * 256 + tid;          // 16B-slot id, 2048 slots (64 rows x 32)
        int row = s >> 5, cs = s & 31;
        const float4* p = (const float4*)(efb + (size_t)s * 8);
        float4 v0 = p[0], v1 = p[1];
        U8v u;
        u.u[0] = cvt_pk_bf16(v0.x, v0.y); u.u[1] = cvt_pk_bf16(v0.z, v0.w);
        u.u[2] = cvt_pk_bf16(v1.x, v1.y); u.u[3] = cvt_pk_bf16(v1.z, v1.w);
        *(U8v*)(smem + row * 512 + ((cs * 16) ^ ((row & 7) << 4))) = u;
    }
    __syncthreads();

    // ---- phase 2: h = ef @ Wlin + b_lin  (M=64, K=256, N=128) ----
    ffrag acc[4][2] = {};
    #pragma unroll
    for (int kk = 0; kk < 8; ++kk) {
        bfrag b0 = *(const bfrag*)(wlinT + col0 * 256 + kk * 32 + q * 8);
        bfrag b1 = *(const bfrag*)(wlinT + col1 * 256 + kk * 32 + q * 8);
        #pragma unroll
        for (int mt = 0; mt < 4; ++mt) {
            int row = 16 * mt + c;
            bfrag a = *(const bfrag*)(smem + row * 512 + ((kk * 64 + q * 16) ^ ((row & 7) << 4)));
            acc[mt][0] = __builtin_amdgcn_mfma_f32_16x16x32_bf16(a, b0, acc[mt][0], 0, 0, 0);
            acc[mt][1] = __builtin_amdgcn_mfma_f32_16x16x32_bf16(a, b1, acc[mt][1], 0, 0, 0);
        }
    }
    {   // fold bias in-place: acc becomes h (kept for residual)
        float bl0 = b_lin[col0], bl1 = b_lin[col1];
        #pragma unroll
        for (int mt = 0; mt < 4; ++mt)
            #pragma unroll
            for (int r = 0; r < 4; ++r) { acc[mt][0][r] += bl0; acc[mt][1][r] += bl1; }
    }

    // ---- phase 3: edge-LN stats (in-wave over c, cross-wave via LDS) ----
    #pragma unroll
    for (int mt = 0; mt < 4; ++mt)
        #pragma unroll
        for (int r = 0; r < 4; ++r) {
            float s  = acc[mt][0][r] + acc[mt][1][r];
            float qv = acc[mt][0][r] * acc[mt][0][r] + acc[mt][1][r] * acc[mt][1][r];
            #pragma unroll
            for (int d = 1; d < 16; d <<= 1) { s += __shfl_xor(s, d); qv += __shfl_xor(qv, d); }
            if (c == 0) {
                int row = 16 * mt + 4 * q + r;
                s_part[w * 128 + row * 2]     = s;
                s_part[w * 128 + row * 2 + 1] = qv;
            }
        }
    __syncthreads();
    if (tid < 64) {
        float s = 0.f, qv = 0.f;
        #pragma unroll
        for (int ww = 0; ww < 4; ++ww) { s += s_part[ww * 128 + tid * 2]; qv += s_part[ww * 128 + tid * 2 + 1]; }
        float mu = s * (1.f / 128.f);
        float var = qv * (1.f / 128.f) - mu * mu;
        s_stat[tid] = mu;
        s_stat[64 + tid] = rsqrtf(var + 1e-5f);
    }
    __syncthreads();

    // ---- phase 4: h_norm -> bf16 LDS [0:16K) ----
    {
        float ge0 = g_edge[col0], ge1 = g_edge[col1];
        float be0 = b_edge[col0], be1 = b_edge[col1];
        #pragma unroll
        for (int mt = 0; mt < 4; ++mt)
            #pragma unroll
            for (int r = 0; r < 4; ++r) {
                int row = 16 * mt + 4 * q + r;
                float mu = s_stat[row], rs = s_stat[64 + row];
                float x0 = (acc[mt][0][r] - mu) * rs * ge0 + be0;
                float x1 = (acc[mt][1][r] - mu) * rs * ge1 + be1;
                *(unsigned short*)(smem + row * 256 + ((col0 * 2) ^ ((row & 7) << 4))) = f2bf1(x0);
                *(unsigned short*)(smem + row * 256 + ((col1 * 2) ^ ((row & 7) << 4))) = f2bf1(x1);
            }
    }
    __syncthreads();

    // ---- phase 5: FFN1 + gelu (M=64, K=128, N=128) ----
    ffrag acc2[4][2] = {};
    #pragma unroll
    for (int kk = 0; kk < 4; ++kk) {
        bfrag b0 = *(const bfrag*)(w1T + col0 * 128 + kk * 32 + q * 8);
        bfrag b1 = *(const bfrag*)(w1T + col1 * 128 + kk * 32 + q * 8);
        #pragma unroll
        for (int mt = 0; mt < 4; ++mt) {
            int row = 16 * mt + c;
            bfrag a = *(const bfrag*)(smem + row * 256 + ((kk * 64 + q * 16) ^ ((row & 7) << 4)));
            acc2[mt][0] = __builtin_amdgcn_mfma_f32_16x16x32_bf16(a, b0, acc2[mt][0], 0, 0, 0);
            acc2[mt][1] = __builtin_amdgcn_mfma_f32_16x16x32_bf16(a, b1, acc2[mt][1], 0, 0, 0);
        }
    }
    {
        float b10 = b1[col0], b11 = b1[col1];
        #pragma unroll
        for (int mt = 0; mt < 4; ++mt)
            #pragma unroll
            for (int j = 0; j < 2; ++j) {
                int col = j ? col1 : col0;
                float bb = j ? b11 : b10;
                #pragma unroll
                for (int r = 0; r < 4; ++r) {
                    int row = 16 * mt + 4 * q + r;
                    float x = acc2[mt][j][r] + bb;
                    float y = 0.7978845608028654f * x * (1.f + 0.044715f * x * x);
                    float e;
                    asm("v_exp_f32 %0, %1" : "=v"(e) : "v"(-2.885390081777927f * y));
                    float rcp;
                    asm("v_rcp_f32 %0, %1" : "=v"(rcp) : "v"(1.f + e));
                    float ge = x * rcp;
                    *(unsigned short*)(smem + 16384 + row * 256 + ((col * 2) ^ ((row & 7) << 4))) = f2bf1(ge);
                }
            }
    }
    __syncthreads();

    // ---- phase 6: FFN2 + residual -> edge_output; masked aggregation ----
    ffrag acc3[4][2] = {};
    #pragma unroll
    for (int kk = 0; kk < 4; ++kk) {
        bfrag b0 = *(const bfrag*)(w2T + col0 * 128 + kk * 32 + q * 8);
        bfrag b1 = *(const bfrag*)(w2T + col1 * 128 + kk * 32 + q * 8);
        #pragma unroll
        for (int mt = 0; mt < 4; ++mt) {
            int row = 16 * mt + c;
            bfrag a = *(const bfrag*)(smem + 16384 + row * 256 + ((kk * 64 + q * 16) ^ ((row & 7) << 4)));
            acc3[mt][0] = __builtin_amdgcn_mfma_f32_16x16x32_bf16(a, b0, acc3[mt][0], 0, 0, 0);
            acc3[mt][1] = __builtin_amdgcn_mfma_f32_16x16x32_bf16(a, b1, acc3[mt][1], 0, 0, 0);
        }
    }
    {
        float b20 = b2[col0], b21 = b2[col1];
        float* eo = out_edge + (size_t)row_base * 128;
        float nvA0 = 0.f, nvA1 = 0.f, nvB0 = 0.f, nvB1 = 0.f;
        #pragma unroll
        for (int mt = 0; mt < 4; ++mt)
            #pragma unroll
            for (int r = 0; r < 4; ++r) {
                int row = 16 * mt + 4 * q + r;
                float mk = s_mask[row];
                float v0 = acc3[mt][0][r] + b20 + acc[mt][0][r];
                float v1 = acc3[mt][1][r] + b21 + acc[mt][1][r];
                eo[row * 128 + col0] = v0;
                eo[row * 128 + col1] = v1;
                if (mt < 2) { nvA0 += mk * v0; nvA1 += mk * v1; }
                else        { nvB0 += mk * v0; nvB1 += mk * v1; }
            }
        nvA0 += __shfl_xor(nvA0, 16); nvA0 += __shfl_xor(nvA0, 32);
        nvA1 += __shfl_xor(nvA1, 16); nvA1 += __shfl_xor(nvA1, 32);
        nvB0 += __shfl_xor(nvB0, 16); nvB0 += __shfl_xor(nvB0, 32);
        nvB1 += __shfl_xor(nvB1, 16); nvB1 += __shfl_xor(nvB1, 32);
        if (q == 0) {
            s_nv[col0] = nvA0;       s_nv[col1] = nvA1;
            s_nv[128 + col0] = nvB0; s_nv[128 + col1] = nvB1;
        }
    }
    __syncthreads();

    // ---- phase 7: node LN (wave 0 -> node n0, wave 1 -> node n0+1) ----
    if (w < 2) {
        float v0 = s_nv[w * 128 + lane], v1 = s_nv[w * 128 + 64 + lane];
        float s = v0 + v1, qv = v0 * v0 + v1 * v1;
        #pragma unroll
        for (int d = 1; d < 64; d <<= 1) { s += __shfl_xor(s, d); qv += __shfl_xor(qv, d); }
        float mu = s * (1.f / 128.f);
        float rstd = rsqrtf(qv * (1.f / 128.f) - mu * mu + 1e-5f);
        size_t base = (size_t)(n0 + w) * 128;
        out_node[base + lane]      = (v0 - mu) * rstd * g_node[lane]      + b_node[lane];
        out_node[base + 64 + lane] = (v1 - mu) * rstd * g_node[64 + lane] + b_node[64 + lane];
    }
}

extern "C" void kernel_launch(void* const* d_in, const int* in_sizes, int n_in,
                              void* d_out, int out_size, void* d_ws, size_t ws_size,
                              hipStream_t stream) {
    const float* ef     = (const float*)d_in[0];
    const int*   mask   = (const int*)d_in[1];
    const float* Wlin   = (const float*)d_in[2];
    const float* b_lin  = (const float*)d_in[3];
    const float* g_edge = (const float*)d_in[4];
    const float* b_edge = (const float*)d_in[5];
    const float* W1     = (const float*)d_in[6];
    const float* b1     = (const float*)d_in[7];
    const float* W2     = (const float*)d_in[8];
    const float* b2     = (const float*)d_in[9];
    const float* g_node = (const float*)d_in[10];
    const float* b_node = (const float*)d_in[11];

    int N = in_sizes[0] / (32 * 256);

    unsigned short* wlinT = (unsigned short*)d_ws;       // [128][256]
    unsigned short* w1T   = wlinT + 128 * 256;           // [128][128]
    unsigned short* w2T   = w1T + 128 * 128;             // [128][128]

    float* out_node = (float*)d_out;
    float* out_edge = out_node + (size_t)N * 128;

    prep_kernel<<<128, 256, 0, stream>>>(Wlin, W1, W2, wlinT, w1T, w2T);
    int npairs = (N + 1) / 2;
    fused_kernel<<<npairs, 256, 0, stream>>>(ef, mask, wlinT, w1T, w2T,
                                             b_lin, g_edge, b_edge, b1, b2,
                                             g_node, b_node, out_node, out_edge, N);
}

// Round 7
// 356.538 us; speedup vs baseline: 1.9688x; 1.1113x over previous
//
#include <hip/hip_runtime.h>

typedef __attribute__((ext_vector_type(8))) short bfrag;   // 8 x bf16 (4 VGPRs)
typedef __attribute__((ext_vector_type(4))) float ffrag;   // 4 x f32 accum

struct alignas(16) U8v { unsigned int u[4]; };

__device__ __forceinline__ unsigned int cvt_pk_bf16(float lo, float hi) {
    unsigned int r;
    asm("v_cvt_pk_bf16_f32 %0, %1, %2" : "=v"(r) : "v"(lo), "v"(hi));
    return r;
}
__device__ __forceinline__ unsigned short f2bf1(float x) {
    return (unsigned short)cvt_pk_bf16(x, x);
}

// ---- prep: transpose + bf16-convert weights into workspace ----
__global__ void prep_kernel(const float* __restrict__ Wlin,
                            const float* __restrict__ W1,
                            const float* __restrict__ W2,
                            unsigned short* __restrict__ wlinT,
                            unsigned short* __restrict__ w1T,
                            unsigned short* __restrict__ w2T) {
    int idx = blockIdx.x * 256 + threadIdx.x;           // 0..32767
    {   // W_lin [256][128] -> wlinT [128][256]
        int e = idx >> 7, h = idx & 127;
        wlinT[h * 256 + e] = f2bf1(Wlin[idx]);
    }
    if (idx < 128 * 128) {  // W1/W2 [128][128] -> transposed
        int h = idx >> 7, f = idx & 127;
        w1T[f * 128 + h] = f2bf1(W1[idx]);
        w2T[f * 128 + h] = f2bf1(W2[idx]);
    }
}

// ---- fused kernel: 1 block = 2 nodes = 64 edge rows, 512 threads (8 waves).
// Wave w owns 16 output cols (col = 16w + c): per-thread acc sets are 16 regs
// (r2's proven no-spill shape). LDS 38.7KB -> 4 blocks/CU; (512,4) = 128-reg
// budget, est. footprint ~90 -> no spill (r4/r5/r6 spill evidence).
__global__ __launch_bounds__(512, 4) void fused_kernel(
    const float* __restrict__ ef, const int* __restrict__ mask,
    const unsigned short* __restrict__ wlinT,
    const unsigned short* __restrict__ w1T,
    const unsigned short* __restrict__ w2T,
    const float* __restrict__ b_lin, const float* __restrict__ g_edge,
    const float* __restrict__ b_edge, const float* __restrict__ b1,
    const float* __restrict__ b2, const float* __restrict__ g_node,
    const float* __restrict__ b_node,
    float* __restrict__ out_node, float* __restrict__ out_edge, int N) {

    __shared__ char  smem[32768];   // phase1-2: ef bf16 [64 rows x 512B, swz]
                                    // later: [0:16K) h_norm bf16 [64x256B, swz], [16K:32K) gelu
    __shared__ float s_part[1024];  // LN partials: w*128 + row*2 + {sum,sq}
    __shared__ float s_stat[128];   // [0:64) mu, [64:128) rstd
    __shared__ float s_mask[64];
    __shared__ float s_nv[256];     // [node][128] aggregated node vals

    const int tid = threadIdx.x;
    const int w = tid >> 6, lane = tid & 63, q = lane >> 4, c = lane & 15;
    const int col = 16 * w + c;

    // tail safety (N even in practice): overlap previous rows, stores idempotent
    int row_base = blockIdx.x * 64;
    if (row_base + 64 > N * 32) row_base = N * 32 - 64;
    const int n0 = row_base >> 5;                        // first of 2 nodes
    const float* efb = ef + (size_t)row_base * 256;

    if (tid < 64) s_mask[tid] = (mask[(size_t)row_base + tid] != 0) ? 1.f : 0.f;

    // ---- phase 1: stage 64 rows of edge_features -> bf16 LDS (swizzled) ----
    #pragma unroll
    for (int i = 0; i < 4; ++i) {
        int s = i * 512 + tid;          // 16B-slot id, 2048 slots (64 rows x 32)
        int row = s >> 5, cs = s & 31;
        const float4* p = (const float4*)(efb + (size_t)s * 8);
        float4 v0 = p[0], v1 = p[1];
        U8v u;
        u.u[0] = cvt_pk_bf16(v0.x, v0.y); u.u[1] = cvt_pk_bf16(v0.z, v0.w);
        u.u[2] = cvt_pk_bf16(v1.x, v1.y); u.u[3] = cvt_pk_bf16(v1.z, v1.w);
        *(U8v*)(smem + row * 512 + ((cs * 16) ^ ((row & 7) << 4))) = u;
    }
    __syncthreads();

    // ---- phase 2: h = ef @ Wlin + b_lin  (M=64, K=256, N=128) ----
    ffrag acc[4] = {};
    #pragma unroll
    for (int kk = 0; kk < 8; ++kk) {
        bfrag b = *(const bfrag*)(wlinT + col * 256 + kk * 32 + q * 8);
        #pragma unroll
        for (int mt = 0; mt < 4; ++mt) {
            int row = 16 * mt + c;
            bfrag a = *(const bfrag*)(smem + row * 512 + ((kk * 64 + q * 16) ^ ((row & 7) << 4)));
            acc[mt] = __builtin_amdgcn_mfma_f32_16x16x32_bf16(a, b, acc[mt], 0, 0, 0);
        }
    }
    {   // fold bias in-place: acc becomes h (kept for residual)
        float bl = b_lin[col];
        #pragma unroll
        for (int mt = 0; mt < 4; ++mt)
            #pragma unroll
            for (int r = 0; r < 4; ++r) acc[mt][r] += bl;
    }

    // ---- phase 3: edge-LN stats (in-wave over 16 c-lanes, cross-wave via LDS) ----
    #pragma unroll
    for (int mt = 0; mt < 4; ++mt)
        #pragma unroll
        for (int r = 0; r < 4; ++r) {
            float s = acc[mt][r], qv = acc[mt][r] * acc[mt][r];
            #pragma unroll
            for (int d = 1; d < 16; d <<= 1) { s += __shfl_xor(s, d); qv += __shfl_xor(qv, d); }
            if (c == 0) {
                int row = 16 * mt + 4 * q + r;
                s_part[w * 128 + row * 2]     = s;
                s_part[w * 128 + row * 2 + 1] = qv;
            }
        }
    __syncthreads();
    if (tid < 64) {
        float s = 0.f, qv = 0.f;
        #pragma unroll
        for (int ww = 0; ww < 8; ++ww) { s += s_part[ww * 128 + tid * 2]; qv += s_part[ww * 128 + tid * 2 + 1]; }
        float mu = s * (1.f / 128.f);
        float var = qv * (1.f / 128.f) - mu * mu;
        s_stat[tid] = mu;
        s_stat[64 + tid] = rsqrtf(var + 1e-5f);
    }
    __syncthreads();

    // ---- phase 4: h_norm -> bf16 LDS [0:16K) ----
    {
        float ge = g_edge[col], be = b_edge[col];
        #pragma unroll
        for (int mt = 0; mt < 4; ++mt)
            #pragma unroll
            for (int r = 0; r < 4; ++r) {
                int row = 16 * mt + 4 * q + r;
                float x = (acc[mt][r] - s_stat[row]) * s_stat[64 + row] * ge + be;
                *(unsigned short*)(smem + row * 256 + ((col * 2) ^ ((row & 7) << 4))) = f2bf1(x);
            }
    }
    __syncthreads();

    // ---- phase 5: FFN1 + gelu (M=64, K=128, N=128) ----
    ffrag acc2[4] = {};
    #pragma unroll
    for (int kk = 0; kk < 4; ++kk) {
        bfrag b = *(const bfrag*)(w1T + col * 128 + kk * 32 + q * 8);
        #pragma unroll
        for (int mt = 0; mt < 4; ++mt) {
            int row = 16 * mt + c;
            bfrag a = *(const bfrag*)(smem + row * 256 + ((kk * 64 + q * 16) ^ ((row & 7) << 4)));
            acc2[mt] = __builtin_amdgcn_mfma_f32_16x16x32_bf16(a, b, acc2[mt], 0, 0, 0);
        }
    }
    {
        float b1c = b1[col];
        #pragma unroll
        for (int mt = 0; mt < 4; ++mt)
            #pragma unroll
            for (int r = 0; r < 4; ++r) {
                int row = 16 * mt + 4 * q + r;
                float x = acc2[mt][r] + b1c;
                float y = 0.7978845608028654f * x * (1.f + 0.044715f * x * x);
                float e;
                asm("v_exp_f32 %0, %1" : "=v"(e) : "v"(-2.885390081777927f * y));
                float rcp;
                asm("v_rcp_f32 %0, %1" : "=v"(rcp) : "v"(1.f + e));
                float ge = x * rcp;
                *(unsigned short*)(smem + 16384 + row * 256 + ((col * 2) ^ ((row & 7) << 4))) = f2bf1(ge);
            }
    }
    __syncthreads();

    // ---- phase 6: FFN2 + residual -> edge_output; masked aggregation ----
    ffrag acc3[4] = {};
    #pragma unroll
    for (int kk = 0; kk < 4; ++kk) {
        bfrag b = *(const bfrag*)(w2T + col * 128 + kk * 32 + q * 8);
        #pragma unroll
        for (int mt = 0; mt < 4; ++mt) {
            int row = 16 * mt + c;
            bfrag a = *(const bfrag*)(smem + 16384 + row * 256 + ((kk * 64 + q * 16) ^ ((row & 7) << 4)));
            acc3[mt] = __builtin_amdgcn_mfma_f32_16x16x32_bf16(a, b, acc3[mt], 0, 0, 0);
        }
    }
    {
        float b2c = b2[col];
        float* eo = out_edge + (size_t)row_base * 128;
        float nvA = 0.f, nvB = 0.f;       // node 0 (rows 0-31), node 1 (rows 32-63)
        #pragma unroll
        for (int mt = 0; mt < 4; ++mt)
            #pragma unroll
            for (int r = 0; r < 4; ++r) {
                int row = 16 * mt + 4 * q + r;
                float v = acc3[mt][r] + b2c + acc[mt][r];
                eo[row * 128 + col] = v;
                float mv = s_mask[row] * v;
                if (mt < 2) nvA += mv; else nvB += mv;
            }
        nvA += __shfl_xor(nvA, 16); nvA += __shfl_xor(nvA, 32);
        nvB += __shfl_xor(nvB, 16); nvB += __shfl_xor(nvB, 32);
        if (q == 0) { s_nv[col] = nvA; s_nv[128 + col] = nvB; }
    }
    __syncthreads();

    // ---- phase 7: node LN (wave 0 -> node n0, wave 1 -> node n0+1) ----
    if (w < 2) {
        float v0 = s_nv[w * 128 + lane], v1 = s_nv[w * 128 + 64 + lane];
        float s = v0 + v1, qv = v0 * v0 + v1 * v1;
        #pragma unroll
        for (int d = 1; d < 64; d <<= 1) { s += __shfl_xor(s, d); qv += __shfl_xor(qv, d); }
        float mu = s * (1.f / 128.f);
        float rstd = rsqrtf(qv * (1.f / 128.f) - mu * mu + 1e-5f);
        size_t base = (size_t)(n0 + w) * 128;
        out_node[base + lane]      = (v0 - mu) * rstd * g_node[lane]      + b_node[lane];
        out_node[base + 64 + lane] = (v1 - mu) * rstd * g_node[64 + lane] + b_node[64 + lane];
    }
}

extern "C" void kernel_launch(void* const* d_in, const int* in_sizes, int n_in,
                              void* d_out, int out_size, void* d_ws, size_t ws_size,
                              hipStream_t stream) {
    const float* ef     = (const float*)d_in[0];
    const int*   mask   = (const int*)d_in[1];
    const float* Wlin   = (const float*)d_in[2];
    const float* b_lin  = (const float*)d_in[3];
    const float* g_edge = (const float*)d_in[4];
    const float* b_edge = (const float*)d_in[5];
    const float* W1     = (const float*)d_in[6];
    const float* b1     = (const float*)d_in[7];
    const float* W2     = (const float*)d_in[8];
    const float* b2     = (const float*)d_in[9];
    const float* g_node = (const float*)d_in[10];
    const float* b_node = (const float*)d_in[11];

    int N = in_sizes[0] / (32 * 256);

    unsigned short* wlinT = (unsigned short*)d_ws;       // [128][256]
    unsigned short* w1T   = wlinT + 128 * 256;           // [128][128]
    unsigned short* w2T   = w1T + 128 * 128;             // [128][128]

    float* out_node = (float*)d_out;
    float* out_edge = out_node + (size_t)N * 128;

    prep_kernel<<<128, 256, 0, stream>>>(Wlin, W1, W2, wlinT, w1T, w2T);
    int npairs = (N + 1) / 2;
    fused_kernel<<<npairs, 512, 0, stream>>>(ef, mask, wlinT, w1T, w2T,
                                             b_lin, g_edge, b_edge, b1, b2,
                                             g_node, b_node, out_node, out_edge, N);
}